// Round 6
// baseline (93.326 us; speedup 1.0000x reference)
//
#include <hip/hip_runtime.h>

// SinePredictor:
//   s = h[edges[0]]; o = h[edges[1]]            [E,128] fp32 gathers
//   score = sin(s-o) @ W.T + b                  [E,1]
//   score = softmax over consecutive pairs      [E/2,2] -> [E,1]
//   out = concat(score, score > 0.5)            2*E floats
//
// Evidence ledger:
//   R2 fp32 d_in, ~2 rows in flight/wave:  97 us, FETCH 306 MB (3.15 TB/s)
//   R3/R4 bf16-in-ws variants:            ~163 us (ws gathers 4x slower/byte;
//                                          plan abandoned)
//   R5 fp32 quarter-waves, VGPR=28(!):     90 us, FETCH 303 MB (3.45 TB/s)
//     -> compiler sank loads next to uses; intended 16-rows-in-flight never
//        happened (28 VGPR < 32 needed just for the data). MLP theory untested.
// R6: identical structure + __builtin_amdgcn_sched_barrier(0) between the 16
//     row loads and the compute: forces all 8 dwordx4/lane outstanding.
//     VGPR_Count is the built-in check (expect ~80-100). If BW still ~3.4 TB/s
//     with confirmed MLP -> random-gather machine ceiling -> roofline.

constexpr int DIMS = 128;

__global__ __launch_bounds__(256) void sine_predictor_kernel(
    const float* __restrict__ h,
    const int*   __restrict__ edges,   // [2, E] int32
    const float* __restrict__ W,       // [1, 128]
    const float* __restrict__ b,       // [1]
    float*       __restrict__ out,     // [2*E]: scores then mask
    int n_edges)
{
    const int lane    = threadIdx.x & 63;
    const int sub     = lane & 15;     // floats sub*8 .. sub*8+7 of the row
    const int quarter = lane >> 4;     // which of 4 consecutive edges
    const int wave_id = blockIdx.x * (blockDim.x >> 6) + (threadIdx.x >> 6);
    const int n_waves = gridDim.x * (blockDim.x >> 6);
    const int n_ch    = (n_edges + 3) >> 2;   // chunks of 4 edges (2 pairs)

    const float4 wl  = reinterpret_cast<const float4*>(W)[sub * 2 + 0];
    const float4 wh  = reinterpret_cast<const float4*>(W)[sub * 2 + 1];
    const float bias = b[0];

    for (int c = wave_id; c < n_ch; c += 2 * n_waves) {
        const int  c2   = c + n_waves;
        const bool has2 = c2 < n_ch;

        // ---- index loads (8 independent dwords) ----
        const int eA  = 4 * c + quarter;
        const int eAc = min(eA, n_edges - 1);
        const int eB  = has2 ? 4 * c2 + quarter : eAc;
        const int eBc = min(eB, n_edges - 1);

        const int srcA = edges[eAc];
        const int objA = edges[n_edges + eAc];
        const int srcB = edges[eBc];
        const int objB = edges[n_edges + eBc];

        // ---- all 16 row-fragment loads (8 dwordx4 per lane) ----
        const float4* sAr = reinterpret_cast<const float4*>(h + (size_t)srcA * DIMS);
        const float4* oAr = reinterpret_cast<const float4*>(h + (size_t)objA * DIMS);
        const float4* sBr = reinterpret_cast<const float4*>(h + (size_t)srcB * DIMS);
        const float4* oBr = reinterpret_cast<const float4*>(h + (size_t)objB * DIMS);

        const float4 sA0 = sAr[sub * 2 + 0];
        const float4 sA1 = sAr[sub * 2 + 1];
        const float4 oA0 = oAr[sub * 2 + 0];
        const float4 oA1 = oAr[sub * 2 + 1];
        const float4 sB0 = sBr[sub * 2 + 0];
        const float4 sB1 = sBr[sub * 2 + 1];
        const float4 oB0 = oBr[sub * 2 + 0];
        const float4 oB1 = oBr[sub * 2 + 1];

        // Scheduler fence: no compute may be hoisted above this point, no load
        // may sink below it -> all 8 dwordx4 stay outstanding together.
        // (Next iteration's loads MAY still be hoisted into the compute below
        // - only this point is pinned.)
        __builtin_amdgcn_sched_barrier(0);

        // ---- compute ----
        float xA = __sinf(sA0.x - oA0.x) * wl.x
                 + __sinf(sA0.y - oA0.y) * wl.y
                 + __sinf(sA0.z - oA0.z) * wl.z
                 + __sinf(sA0.w - oA0.w) * wl.w
                 + __sinf(sA1.x - oA1.x) * wh.x
                 + __sinf(sA1.y - oA1.y) * wh.y
                 + __sinf(sA1.z - oA1.z) * wh.z
                 + __sinf(sA1.w - oA1.w) * wh.w;
        float xB = __sinf(sB0.x - oB0.x) * wl.x
                 + __sinf(sB0.y - oB0.y) * wl.y
                 + __sinf(sB0.z - oB0.z) * wl.z
                 + __sinf(sB0.w - oB0.w) * wl.w
                 + __sinf(sB1.x - oB1.x) * wh.x
                 + __sinf(sB1.y - oB1.y) * wh.y
                 + __sinf(sB1.z - oB1.z) * wh.z
                 + __sinf(sB1.w - oB1.w) * wh.w;

        // ---- reduce within each 16-lane quarter ----
        #pragma unroll
        for (int m = 8; m >= 1; m >>= 1) xA += __shfl_xor(xA, m, 64);
        #pragma unroll
        for (int m = 8; m >= 1; m >>= 1) xB += __shfl_xor(xB, m, 64);
        xA += bias;
        xB += bias;

        // ---- pair softmax: partner quarter via xor lane 16 ----
        // p = 1/(1+exp(other-x)) == softmax; p>0.5 <=> x>other (sign-exact).
        {
            const float other = __shfl_xor(xA, 16, 64);
            const float p = 1.0f / (1.0f + __expf(other - xA));
            if (sub == 0 && eA < n_edges) {
                out[eA]           = p;
                out[n_edges + eA] = (p > 0.5f) ? 1.0f : 0.0f;
            }
        }
        if (has2) {
            const float other = __shfl_xor(xB, 16, 64);
            const float p = 1.0f / (1.0f + __expf(other - xB));
            if (sub == 0 && eB < n_edges) {
                out[eB]           = p;
                out[n_edges + eB] = (p > 0.5f) ? 1.0f : 0.0f;
            }
        }
    }
}

extern "C" void kernel_launch(void* const* d_in, const int* in_sizes, int n_in,
                              void* d_out, int out_size, void* d_ws, size_t ws_size,
                              hipStream_t stream) {
    const float* h     = (const float*)d_in[0];
    const int*   edges = (const int*)d_in[1];
    const float* W     = (const float*)d_in[2];
    const float* b     = (const float*)d_in[3];
    float*       out   = (float*)d_out;

    const int n_edges = in_sizes[1] / 2;   // edges is [2, E]

    // 2048 blocks x 4 waves = 8192 waves; no waves/EU cap (R5's 51% occupancy
    // at (256,6) left residency on the table).
    const int blocks = 2048;
    sine_predictor_kernel<<<blocks, 256, 0, stream>>>(h, edges, W, b, out, n_edges);
}